// Round 4
// baseline (91.941 us; speedup 1.0000x reference)
//
#include <hip/hip_runtime.h>
#include <hip/hip_cooperative_groups.h>
#include <math.h>

namespace cg = cooperative_groups;

// Problem constants (match reference)
static constexpr int Bn = 8;
static constexpr int Nn = 16;
static constexpr int Mn = 4;
static constexpr int Cn = 2;
static constexpr int HWn = 256 * 256;     // 65536
static constexpr int SEGS = 64;           // segments per b
static constexpr int SEGLEN = HWn / SEGS; // 1024
#define GAMMA_F 0.5f
#define MASS_F 0.25f
#define EPS_F 1e-8f

// Partial matrix in ws: rows of 64 floats (one col per segment).
//   rows [0,512):   inter[bn][m]   (row = bn*4+m)
//   rows [512,640): ssum[bn]       (row = 512+bn)
//   rows [640,672): gsum[b][m]     (row = 640+b*4+m)
static constexpr int ROWS = 672;

// One cooperative kernel: 512 blocks = (b, seg). Phase A computes partials
// (gt read ONCE from HBM); grid sync; block 0 reduces + coupling + losses.
__global__ __launch_bounds__(256) void fused_kernel(
    const float* __restrict__ sample, const int* __restrict__ gt,
    const float* __restrict__ prob, const float* __restrict__ prob_gt,
    float* __restrict__ part, float* __restrict__ out) {
  int seg = blockIdx.x & (SEGS - 1);
  int b = blockIdx.x >> 6;
  int tid = threadIdx.x;
  int w = tid >> 6;
  int lane = tid & 63;
  size_t segoff = (size_t)seg * SEGLEN;

  const int* gtb = gt + ((size_t)b * Mn) * HWn + segoff;
  const float* sb = sample + (size_t)b * Nn * Cn * HWn + HWn + segoff;

  float ss[4] = {0.f, 0.f, 0.f, 0.f};
  float im[4][4] = {};
  float cnt[4] = {0.f, 0.f, 0.f, 0.f};

#pragma unroll
  for (int q = 0; q < 4; ++q) {
    int idx = q * 64 + lane;
    int4 g0 = reinterpret_cast<const int4*>(gtb + 0 * HWn)[idx];
    int4 g1 = reinterpret_cast<const int4*>(gtb + 1 * HWn)[idx];
    int4 g2 = reinterpret_cast<const int4*>(gtb + 2 * HWn)[idx];
    int4 g3 = reinterpret_cast<const int4*>(gtb + 3 * HWn)[idx];
    float mf[4][4];  // [e][m], all compile-time indexed (unrolled)
    {
      int a0[4] = {g0.x, g0.y, g0.z, g0.w};
      int a1[4] = {g1.x, g1.y, g1.z, g1.w};
      int a2[4] = {g2.x, g2.y, g2.z, g2.w};
      int a3[4] = {g3.x, g3.y, g3.z, g3.w};
#pragma unroll
      for (int e = 0; e < 4; ++e) {
        mf[e][0] = (a0[e] == 1) ? 1.f : 0.f;
        mf[e][1] = (a1[e] == 1) ? 1.f : 0.f;
        mf[e][2] = (a2[e] == 1) ? 1.f : 0.f;
        mf[e][3] = (a3[e] == 1) ? 1.f : 0.f;
      }
    }
#pragma unroll
    for (int m = 0; m < 4; ++m)
      cnt[m] += (mf[0][m] + mf[1][m]) + (mf[2][m] + mf[3][m]);
#pragma unroll
    for (int nn = 0; nn < 4; ++nn) {
      const float* spn = sb + (size_t)(w * 4 + nn) * (Cn * HWn);
      float4 x = reinterpret_cast<const float4*>(spn)[idx];
      float xs[4] = {x.x, x.y, x.z, x.w};
#pragma unroll
      for (int e = 0; e < 4; ++e) {
        float v = xs[e];
        ss[nn] += v;
#pragma unroll
        for (int m = 0; m < 4; ++m) im[nn][m] = fmaf(v, mf[e][m], im[nn][m]);
      }
    }
  }

  // Stage per-lane partials in LDS (rows padded to 68 floats).
  __shared__ __align__(16) float red[4][20][68];
  __shared__ __align__(16) float redc[4][68];
#pragma unroll
  for (int nn = 0; nn < 4; ++nn) {
    red[w][nn * 5 + 0][lane] = ss[nn];
#pragma unroll
    for (int m = 0; m < 4; ++m) red[w][nn * 5 + 1 + m][lane] = im[nn][m];
  }
  if (w == 0) {
#pragma unroll
    for (int m = 0; m < 4; ++m) redc[m][lane] = cnt[m];
  }
  __syncthreads();

  if (tid < 80) {
    int rw = tid / 20, v = tid % 20;
    const float4* row = reinterpret_cast<const float4*>(&red[rw][v][0]);
    float4 a4 = row[0];
#pragma unroll
    for (int j = 1; j < 16; ++j) {
      float4 t = row[j];
      a4.x += t.x; a4.y += t.y; a4.z += t.z; a4.w += t.w;
    }
    float s = (a4.x + a4.y) + (a4.z + a4.w);
    int n = rw * 4 + v / 5;
    int k = v % 5;
    int bn = b * Nn + n;
    int r = (k == 0) ? (512 + bn) : (bn * Mn + (k - 1));
    part[(size_t)r * SEGS + seg] = s;
  } else if (tid < 84) {
    int m = tid - 80;
    const float4* row = reinterpret_cast<const float4*>(&redc[m][0]);
    float4 a4 = row[0];
#pragma unroll
    for (int j = 1; j < 16; ++j) {
      float4 t = row[j];
      a4.x += t.x; a4.y += t.y; a4.z += t.z; a4.w += t.w;
    }
    float s = (a4.x + a4.y) + (a4.z + a4.w);
    part[(size_t)(640 + b * Mn + m) * SEGS + seg] = s;
  }

  cg::this_grid().sync();

  if (blockIdx.x != 0) return;

  // ---- Phase B (block 0 only): reduce partials, cost, coupling, losses ----
  __shared__ float rows[ROWS];
  __shared__ float s_cost[Bn * Nn * Mn];
  __shared__ float s_red[8];
  int wv = tid >> 6;

  // 672 rows of 64 floats; each wave-iter reduces 4 rows via one float4 load.
#pragma unroll 2
  for (int it = 0; it < ROWS / 16; ++it) {
    int r0 = it * 16 + wv * 4;
    float4 x = reinterpret_cast<const float4*>(part)[(size_t)r0 * 16 + lane];
    float s = (x.x + x.y) + (x.z + x.w);
    s += __shfl_xor(s, 1);
    s += __shfl_xor(s, 2);
    s += __shfl_xor(s, 4);
    s += __shfl_xor(s, 8);
    if ((lane & 15) == 0) rows[r0 + (lane >> 4)] = s;
  }
  __syncthreads();

  for (int idx = tid; idx < Bn * Nn * Mn; idx += 256) {
    int m = idx & 3;
    int bn = idx >> 2;
    int bb = bn >> 4;
    float inter = rows[idx];
    float uni = rows[512 + bn] + rows[640 + (bb << 2) + m] - inter;
    s_cost[idx] = 1.0f - (inter + 1.0f) / (uni + 1.0f);
  }
  __syncthreads();

  // Coupling: one lane per (b,n); register/shuffle only (verified R2 code).
  float seg_part = 0.f, kl_part = 0.f;
  if (tid < Bn * Nn) {
    int bb = tid >> 4;
    int n = tid & 15;
    int base = (tid & 63) & ~15;

    float4 cv = *reinterpret_cast<const float4*>(&s_cost[tid * Mn]);
    float cc0 = cv.x, cc1 = cv.y, cc2 = cv.z, cc3 = cv.w;
    float pg0 = prob_gt[bb * Mn + 0], pg1 = prob_gt[bb * Mn + 1];
    float pg2 = prob_gt[bb * Mn + 2], pg3 = prob_gt[bb * Mn + 3];

    float m0 = cc0, m1 = cc1, m2 = cc2, m3 = cc3;
#pragma unroll
    for (int off = 1; off < 16; off <<= 1) {
      m0 = fminf(m0, __shfl_xor(m0, off));
      m1 = fminf(m1, __shfl_xor(m1, off));
      m2 = fminf(m2, __shfl_xor(m2, off));
      m3 = fminf(m3, __shfl_xor(m3, off));
    }
    int r0 = (m1 < m0) + (m2 < m0) + (m3 < m0);
    int r1 = (m0 <= m1) + (m2 < m1) + (m3 < m1);
    int r2 = (m0 <= m2) + (m1 <= m2) + (m3 < m2);
    int r3 = (m0 <= m3) + (m1 <= m3) + (m2 <= m3);

    float rowsum = 0.f;
    float target = 0.f;
#pragma unroll
    for (int k = 0; k < Mn; ++k) {
      int i = (r0 == k) ? 0 : (r1 == k) ? 1 : (r2 == k) ? 2 : 3;
      float v = (i == 0) ? cc0 : (i == 1) ? cc1 : (i == 2) ? cc2 : cc3;
      float pg = (i == 0) ? pg0 : (i == 1) ? pg1 : (i == 2) ? pg2 : pg3;
      float cap = GAMMA_F - rowsum;
      float excl = 0.f;
#pragma unroll 4
      for (int j = 0; j < Nn; ++j) {
        float vj = __shfl(v, base + j);
        float capj = __shfl(cap, base + j);
        bool pred = (vj < v) || (vj == v && j < n);
        excl += pred ? capj : 0.f;
      }
      float a = fminf(fmaxf(MASS_F - excl, 0.f), cap);
      rowsum += a;
      float p = a * pg * (float)Mn;
      seg_part += p * v;
      target += p;
    }
    kl_part = (target > 0.f)
                  ? target * (logf(target) - logf(prob[tid] + EPS_F))
                  : 0.f;
  }

#pragma unroll
  for (int off = 32; off > 0; off >>= 1) {
    seg_part += __shfl_down(seg_part, off);
    kl_part += __shfl_down(kl_part, off);
  }
  if (lane == 0) { s_red[wv * 2] = seg_part; s_red[wv * 2 + 1] = kl_part; }
  __syncthreads();
  if (tid == 0) {
    float segl = 0.f, kl = 0.f;
    for (int q = 0; q < 4; ++q) { segl += s_red[q * 2]; kl += s_red[q * 2 + 1]; }
    segl /= (float)Bn;
    kl /= (float)(Bn * Nn);
    out[0] = segl + 1.0f * kl;  // BETA = 1
    out[1] = segl;
    out[2] = kl;
  }
}

extern "C" void kernel_launch(void* const* d_in, const int* in_sizes, int n_in,
                              void* d_out, int out_size, void* d_ws, size_t ws_size,
                              hipStream_t stream) {
  const int* gt = (const int*)d_in[0];          // (B,M,H,W) int32
  const float* sample = (const float*)d_in[1];  // (B,N,C,H,W) f32
  const float* prob = (const float*)d_in[2];    // (B,N)
  const float* prob_gt = (const float*)d_in[3]; // (B,M)
  float* out = (float*)d_out;
  float* part = (float*)d_ws;                   // [672][64] f32

  void* args[] = {(void*)&sample, (void*)&gt, (void*)&prob, (void*)&prob_gt,
                  (void*)&part, (void*)&out};
  hipLaunchCooperativeKernel((const void*)fused_kernel, dim3(Bn * SEGS),
                             dim3(256), args, 0, stream);
}

// Round 5
// 22.240 us; speedup vs baseline: 4.1340x; 4.1340x over previous
//
#include <hip/hip_runtime.h>
#include <math.h>

// Problem constants (match reference)
static constexpr int Bn = 8;
static constexpr int Nn = 16;
static constexpr int Mn = 4;
static constexpr int Cn = 2;
static constexpr int HWn = 256 * 256;      // 65536
static constexpr int Sn = 16;              // segments per (b,n)
static constexpr int SEGLEN = HWn / Sn;    // 4096
#define GAMMA_F 0.5f
#define MASS_F 0.25f
#define EPS_F 1e-8f

// Workspace layout (bytes):
//   inter_part [B*N][S][M] f32 : 8192 f = 32768 B @ 0      (contig float4 per s)
//   ssum_part  [B*N][S]    f32 : 2048 f =  8192 B @ 32768
//   gsum_part  [B][S][M]   f32 :  512 f =  2048 B @ 40960

// 2048 blocks = (b, n, s) with b = blockIdx & 7 so all blocks sharing b's gt
// planes land on the same XCD (round-robin dispatch) -> gt re-reads are L2-hits.
__global__ __launch_bounds__(256) void inter_kernel(
    const float* __restrict__ sample, const int* __restrict__ gt,
    float* __restrict__ inter_part, float* __restrict__ ssum_part,
    float* __restrict__ gsum_part) {
  int blk = blockIdx.x;
  int b = blk & 7;
  int r = blk >> 3;   // [0,256)
  int s = r & 15;
  int n = r >> 4;     // [0,16)

  const float* sp = sample + ((((size_t)b * Nn + n) * Cn + 1) * HWn) + (size_t)s * SEGLEN;
  const int* gtb = gt + (size_t)b * Mn * HWn + (size_t)s * SEGLEN;

  float ss = 0.f, im0 = 0.f, im1 = 0.f, im2 = 0.f, im3 = 0.f;
  unsigned int c0 = 0, c1 = 0, c2 = 0, c3 = 0;

  // SEGLEN/4 = 1024 float4 over 256 threads -> 4 iters
#pragma unroll
  for (int q = 0; q < 4; ++q) {
    int i = q * 256 + threadIdx.x;
    float4 x = reinterpret_cast<const float4*>(sp)[i];
    int4 g0 = reinterpret_cast<const int4*>(gtb + 0 * HWn)[i];
    int4 g1 = reinterpret_cast<const int4*>(gtb + 1 * HWn)[i];
    int4 g2 = reinterpret_cast<const int4*>(gtb + 2 * HWn)[i];
    int4 g3 = reinterpret_cast<const int4*>(gtb + 3 * HWn)[i];
    float xs[4] = {x.x, x.y, x.z, x.w};
    int m0[4] = {g0.x, g0.y, g0.z, g0.w};
    int m1[4] = {g1.x, g1.y, g1.z, g1.w};
    int m2[4] = {g2.x, g2.y, g2.z, g2.w};
    int m3[4] = {g3.x, g3.y, g3.z, g3.w};
#pragma unroll
    for (int e = 0; e < 4; ++e) {
      float v = xs[e];
      ss += v;
      bool b0 = (m0[e] == 1), b1 = (m1[e] == 1), b2 = (m2[e] == 1), b3 = (m3[e] == 1);
      im0 += b0 ? v : 0.0f;
      im1 += b1 ? v : 0.0f;
      im2 += b2 ? v : 0.0f;
      im3 += b3 ? v : 0.0f;
      c0 += b0; c1 += b1; c2 += b2; c3 += b3;
    }
  }

  // 64-lane butterfly reduce of 9 values
#pragma unroll
  for (int off = 32; off > 0; off >>= 1) {
    ss  += __shfl_down(ss, off);
    im0 += __shfl_down(im0, off);
    im1 += __shfl_down(im1, off);
    im2 += __shfl_down(im2, off);
    im3 += __shfl_down(im3, off);
    c0  += __shfl_down(c0, off);
    c1  += __shfl_down(c1, off);
    c2  += __shfl_down(c2, off);
    c3  += __shfl_down(c3, off);
  }

  __shared__ float sred[4][5];
  __shared__ unsigned int scnt[4][4];
  int lane = threadIdx.x & 63;
  int wv = threadIdx.x >> 6;
  if (lane == 0) {
    sred[wv][0] = ss; sred[wv][1] = im0; sred[wv][2] = im1;
    sred[wv][3] = im2; sred[wv][4] = im3;
    scnt[wv][0] = c0; scnt[wv][1] = c1; scnt[wv][2] = c2; scnt[wv][3] = c3;
  }
  __syncthreads();
  if (threadIdx.x == 0) {
    float t[5] = {0, 0, 0, 0, 0};
    for (int w = 0; w < 4; ++w)
      for (int v = 0; v < 5; ++v) t[v] += sred[w][v];
    int bn = b * Nn + n;
    ssum_part[(size_t)bn * Sn + s] = t[0];
    float* ip = inter_part + ((size_t)bn * Sn + s) * Mn;  // [bn][s][m]
    ip[0] = t[1]; ip[1] = t[2]; ip[2] = t[3]; ip[3] = t[4];
    if (n == 0) {
      unsigned int cc[4] = {0, 0, 0, 0};
      for (int w = 0; w < 4; ++w)
        for (int m = 0; m < 4; ++m) cc[m] += scnt[w][m];
      float* gp = gsum_part + ((size_t)b * Sn + s) * Mn;  // [b][s][m]
      gp[0] = (float)cc[0]; gp[1] = (float)cc[1];
      gp[2] = (float)cc[2]; gp[3] = (float)cc[3];
    }
  }
}

// Reduce partials (float4-wise: lanes of each float4 ARE the 4 m-accumulators),
// cost, coupling (register/shuffle, proven), losses.
__global__ __launch_bounds__(256) void finish_kernel(
    const float* __restrict__ inter_part, const float* __restrict__ ssum_part,
    const float* __restrict__ gsum_part,
    const float* __restrict__ prob, const float* __restrict__ prob_gt,
    float* __restrict__ out) {
  __shared__ __align__(16) float s_im[Bn * Nn * Mn];   // [bn][m]
  __shared__ float s_ssum[Bn * Nn];
  __shared__ __align__(16) float s_gsum[Bn * Mn];
  __shared__ float s_cost[Bn * Nn * Mn];
  __shared__ float s_red[8];
  int tid = threadIdx.x;

  if (tid < Bn * Nn) {
    // inter: 16 contiguous float4 (one per s), lanes = m
    const float4* ip = reinterpret_cast<const float4*>(&inter_part[(size_t)tid * Sn * Mn]);
    float4 a4 = ip[0];
#pragma unroll
    for (int j = 1; j < 16; ++j) {
      float4 t = ip[j];
      a4.x += t.x; a4.y += t.y; a4.z += t.z; a4.w += t.w;
    }
    *reinterpret_cast<float4*>(&s_im[tid * Mn]) = a4;
    // ssum: 4 float4
    const float4* sp4 = reinterpret_cast<const float4*>(&ssum_part[(size_t)tid * Sn]);
    float4 s4 = sp4[0];
#pragma unroll
    for (int j = 1; j < 4; ++j) {
      float4 t = sp4[j];
      s4.x += t.x; s4.y += t.y; s4.z += t.z; s4.w += t.w;
    }
    s_ssum[tid] = (s4.x + s4.y) + (s4.z + s4.w);
  } else if (tid < 128 + Bn) {
    int b = tid - 128;
    const float4* gp = reinterpret_cast<const float4*>(&gsum_part[(size_t)b * Sn * Mn]);
    float4 a4 = gp[0];
#pragma unroll
    for (int j = 1; j < 16; ++j) {
      float4 t = gp[j];
      a4.x += t.x; a4.y += t.y; a4.z += t.z; a4.w += t.w;
    }
    *reinterpret_cast<float4*>(&s_gsum[b * Mn]) = a4;
  }
  __syncthreads();

  for (int idx = tid; idx < Bn * Nn * Mn; idx += 256) {
    int m = idx & 3;
    int bn = idx >> 2;
    int b = bn >> 4;
    float inter = s_im[idx];
    float uni = s_ssum[bn] + s_gsum[(b << 2) + m] - inter;
    s_cost[idx] = 1.0f - (inter + 1.0f) / (uni + 1.0f);
  }
  __syncthreads();

  // coupling: one lane per (b,n)
  float seg_part = 0.f, kl_part = 0.f;
  if (tid < Bn * Nn) {
    int b = tid >> 4;
    int n = tid & 15;
    int base = (tid & 63) & ~15;

    float4 cv = *reinterpret_cast<const float4*>(&s_cost[tid * Mn]);
    float cc0 = cv.x, cc1 = cv.y, cc2 = cv.z, cc3 = cv.w;
    float pg0 = prob_gt[b * Mn + 0], pg1 = prob_gt[b * Mn + 1];
    float pg2 = prob_gt[b * Mn + 2], pg3 = prob_gt[b * Mn + 3];

    float m0 = cc0, m1 = cc1, m2 = cc2, m3 = cc3;
#pragma unroll
    for (int off = 1; off < 16; off <<= 1) {
      m0 = fminf(m0, __shfl_xor(m0, off));
      m1 = fminf(m1, __shfl_xor(m1, off));
      m2 = fminf(m2, __shfl_xor(m2, off));
      m3 = fminf(m3, __shfl_xor(m3, off));
    }
    int r0 = (m1 < m0) + (m2 < m0) + (m3 < m0);
    int r1 = (m0 <= m1) + (m2 < m1) + (m3 < m1);
    int r2 = (m0 <= m2) + (m1 <= m2) + (m3 < m2);
    int r3 = (m0 <= m3) + (m1 <= m3) + (m2 <= m3);

    float rowsum = 0.f;
    float target = 0.f;
#pragma unroll
    for (int k = 0; k < Mn; ++k) {
      int i = (r0 == k) ? 0 : (r1 == k) ? 1 : (r2 == k) ? 2 : 3;
      float v = (i == 0) ? cc0 : (i == 1) ? cc1 : (i == 2) ? cc2 : cc3;
      float pg = (i == 0) ? pg0 : (i == 1) ? pg1 : (i == 2) ? pg2 : pg3;
      float cap = GAMMA_F - rowsum;
      float excl = 0.f;
#pragma unroll 4
      for (int j = 0; j < Nn; ++j) {
        float vj = __shfl(v, base + j);
        float capj = __shfl(cap, base + j);
        bool pred = (vj < v) || (vj == v && j < n);
        excl += pred ? capj : 0.f;
      }
      float a = fminf(fmaxf(MASS_F - excl, 0.f), cap);
      rowsum += a;
      float p = a * pg * (float)Mn;
      seg_part += p * v;
      target += p;
    }
    kl_part = (target > 0.f)
                  ? target * (logf(target) - logf(prob[tid] + EPS_F))
                  : 0.f;
  }

#pragma unroll
  for (int off = 32; off > 0; off >>= 1) {
    seg_part += __shfl_down(seg_part, off);
    kl_part += __shfl_down(kl_part, off);
  }
  int lane = tid & 63, wv = tid >> 6;
  if (lane == 0) { s_red[wv * 2] = seg_part; s_red[wv * 2 + 1] = kl_part; }
  __syncthreads();
  if (tid == 0) {
    float seg = 0.f, kl = 0.f;
    for (int w = 0; w < 4; ++w) { seg += s_red[w * 2]; kl += s_red[w * 2 + 1]; }
    seg /= (float)Bn;
    kl /= (float)(Bn * Nn);
    out[0] = seg + 1.0f * kl;  // BETA = 1
    out[1] = seg;
    out[2] = kl;
  }
}

extern "C" void kernel_launch(void* const* d_in, const int* in_sizes, int n_in,
                              void* d_out, int out_size, void* d_ws, size_t ws_size,
                              hipStream_t stream) {
  const int* gt = (const int*)d_in[0];          // (B,M,H,W) int32
  const float* sample = (const float*)d_in[1];  // (B,N,C,H,W) f32
  const float* prob = (const float*)d_in[2];    // (B,N)
  const float* prob_gt = (const float*)d_in[3]; // (B,M)
  float* out = (float*)d_out;

  char* ws = (char*)d_ws;
  float* inter_part = (float*)(ws + 0);
  float* ssum_part = (float*)(ws + 32768);
  float* gsum_part = (float*)(ws + 40960);

  inter_kernel<<<Bn * Nn * Sn, 256, 0, stream>>>(sample, gt, inter_part, ssum_part, gsum_part);
  finish_kernel<<<1, 256, 0, stream>>>(inter_part, ssum_part, gsum_part, prob, prob_gt, out);
}